// Round 7
// baseline (244.100 us; speedup 1.0000x reference)
//
#include <hip/hip_runtime.h>
#include <stdint.h>

// ---------------- problem constants ----------------
#define B_ROWS 65536
#define D_IN   784
#define H_DIM  256
#define L_LEAF 64
#define C_CLS  10
#define NSTEP  13            // BK=64 K-steps (primary path)
#define BTILE  40960         // 320 n * 64 k * 2B
#define NSTEP2 25            // BK=32 K-steps (fallback path)
#define BTILE2 20480
#define GAP_THRESH 0.03f

using f32x4    = __attribute__((ext_vector_type(4))) float;
using bf16x8   = __attribute__((ext_vector_type(8))) short;
using ushort8v = __attribute__((ext_vector_type(8))) unsigned short;
using ushort4v = __attribute__((ext_vector_type(4))) unsigned short;

// ---------------- ws layout (bytes) ----------------
#define O_FLAGCNT  0
#define O_CHOICES  4096
#define O_FLAGROWS (O_CHOICES + B_ROWS * 4)                  // 266240
#define O_WT       (O_FLAGROWS + B_ROWS * 4)                 // 528384
#define WT_MAX     532480                                    // BK64 image (BK32 fits too)
#define O_FEAT     (O_WT + WT_MAX)
#define O_WLB      (O_FEAT + (size_t)B_ROWS * H_DIM * 2)
#define WLB_BYTES  ((size_t)L_LEAF * H_DIM * C_CLS * 2)
#define O_XT       (O_WLB + WLB_BYTES)
#define XT_BYTES   ((size_t)(B_ROWS / 64) * NSTEP * 8192)    // 109,051,904
#define WS_BASE    O_WLB
#define WS_WLB     (O_WLB + WLB_BYTES)
#define WS_XT      (O_XT + XT_BYTES)

__device__ __forceinline__ unsigned short f2bf(float f) {
    union { float f; unsigned int u; } c; c.f = f;
    unsigned int u = c.u;
    return (unsigned short)((u + 0x7fffu + ((u >> 16) & 1u)) >> 16);   // RNE
}
__device__ __forceinline__ float bf2f(unsigned short u) {
    union { unsigned int u; float f; } c; c.u = ((unsigned int)u) << 16;
    return c.f;
}
__device__ __forceinline__ unsigned int cvtpk(float a, float b) {
    unsigned int r;
    asm("v_cvt_pk_bf16_f32 %0, %1, %2" : "=v"(r) : "v"(a), "v"(b));
    return r;
}
__device__ __forceinline__ void gload_lds16(const void* g, void* l) {
    __builtin_amdgcn_global_load_lds(
        (const __attribute__((address_space(1))) unsigned int*)g,
        (__attribute__((address_space(3))) unsigned int*)l, 16, 0, 0);
}

// =================== PRIMARY PATH (ws >= WS_XT) ===================

// ---- K0 (BK=64 B image; r2-r4 format, measured 0 bank conflicts) ----
// chunk (n, c4) at byte ts*40960 + n*128 + c4*16 holds k-chunk (c4 ^ (n&7)).
__global__ void k0_prep64(const float* __restrict__ Wf, const float* __restrict__ Wr,
                          unsigned short* __restrict__ Wt, unsigned int* __restrict__ flagcnt) {
    if (blockIdx.x == 0 && threadIdx.x == 0) *flagcnt = 0u;
    int id = blockIdx.x * 256 + threadIdx.x;   // 33280 chunks
    if (id >= 33280) return;
    int ts = id / 2560;
    int r  = id % 2560;
    int n  = r % 320;
    int c4 = r / 320;                           // 0..7 (position)
    int ks = ts * 64 + ((c4 ^ (n & 7)) << 3);   // content k
    unsigned short v[8];
    #pragma unroll
    for (int j = 0; j < 8; ++j) {
        int k = ks + j;
        float f = 0.f;
        if (k < D_IN)
            f = (n < H_DIM) ? Wf[(size_t)k * H_DIM + n]
                            : Wr[(size_t)k * L_LEAF + (n - H_DIM)];
        v[j] = f2bf(f);
    }
    *(ushort8v*)((char*)Wt + (size_t)ts * BTILE + (size_t)(n * 8 + c4) * 16) = *(ushort8v*)v;
}

// ---- K0x: x fp32 -> bf16 tiled/swizzled A image ----
// Tile (bm, ts): 4 slices (mt) of 16 rows x 64 k = 2KB each, at
//   ((bm*13 + ts)*4 + mt)*2048;  chunk (ic, pos) holds k-chunk (pos ^ (ic&7)).
// Thread (row, c): 8 consecutive lanes (cc=0..7) fill one full 128B line.
__global__ void k0x(const float* __restrict__ x, unsigned short* __restrict__ Xt) {
    int id = blockIdx.x * 256 + threadIdx.x;    // 65536*104 = 6,815,744 exact
    int row = id / 104, c = id % 104;           // c = k/8 (padded to 832)
    int ts = c >> 3, cc = c & 7;
    int bm = row >> 6, rr = row & 63, mt = rr >> 4, ic = rr & 15;
    size_t dst = ((size_t)(bm * NSTEP + ts) * 4 + mt) * 2048
               + (size_t)(ic * 128 + ((cc ^ (ic & 7)) << 4));
    ushort8v v = (ushort8v){0,0,0,0,0,0,0,0};
    if (c < 98) {                                // k = c*8 .. c*8+7 all < 784
        const float* xp = x + (size_t)row * D_IN + c * 8;
        f32x4 lo = *(const f32x4*)(xp);
        f32x4 hi = *(const f32x4*)(xp + 4);
        v.s0 = f2bf(lo.x); v.s1 = f2bf(lo.y); v.s2 = f2bf(lo.z); v.s3 = f2bf(lo.w);
        v.s4 = f2bf(hi.x); v.s5 = f2bf(hi.y); v.s6 = f2bf(hi.z); v.s7 = f2bf(hi.w);
    }
    *(ushort8v*)((char*)Xt + dst) = v;
}

// ---- K0b: Wl -> bf16 ----
__global__ void k0b_wl(const float* __restrict__ Wl, unsigned short* __restrict__ Wlb) {
    int i = (blockIdx.x * 256 + threadIdx.x) * 4;
    f32x4 v = *(const f32x4*)(Wl + i);
    ushort4v h; h.x = f2bf(v.x); h.y = f2bf(v.y); h.z = f2bf(v.z); h.w = f2bf(v.w);
    *(ushort4v*)(Wlb + i) = h;
}

// ---- K1 (primary): all-LDS m97 structure ----
// grid = 1024 x 256 (4 waves); LDS 48KB single-buffer -> 3 blocks/CU.
// Per step: 12 gload_lds -> barrier -> 8 A-dsread + {10 B-dsread, 40 MFMA} -> barrier.
__global__ __launch_bounds__(256, 3) void k1_xt(
    const unsigned short* __restrict__ Xt, const unsigned short* __restrict__ Wt,
    const float* __restrict__ bfv, const float* __restrict__ brv,
    unsigned short* __restrict__ feat, int* __restrict__ choices,
    unsigned int* __restrict__ flagcnt, int* __restrict__ flagrows)
{
    __shared__ __align__(16) char L[49152];    // A: [0,8192), B: [8192,49152)

    const int t = threadIdx.x, w = t >> 6, l = t & 63, q = l >> 4, ic = l & 15;
    const int bm0 = blockIdx.x * 64;

    f32x4 acc[4][5];
    #pragma unroll
    for (int a = 0; a < 4; ++a)
        #pragma unroll
        for (int b = 0; b < 5; ++b)
            acc[a][b] = (f32x4){0.f, 0.f, 0.f, 0.f};

    const int e7   = ic & 7;
    const int p0   = ((q ^ e7) << 4);          // kk=0 chunk position * 16B
    const int p1   = (((4 + q) ^ e7) << 4);    // kk=1
    const int arow = ic * 128;
    const int ntb  = w * 5;

    for (int ts = 0; ts < NSTEP; ++ts) {
        // ---- stage A (8KB) + B (40KB), linear LDS dst
        const char* asrc = (const char*)Xt + (size_t)(blockIdx.x * NSTEP + ts) * 8192;
        gload_lds16(asrc + t * 16,          L + t * 16);
        gload_lds16(asrc + (256 + t) * 16,  L + (256 + t) * 16);
        const char* bsrc = (const char*)Wt + (size_t)ts * BTILE;
        #pragma unroll
        for (int i = 0; i < 10; ++i) {
            int cid = i * 256 + t;
            gload_lds16(bsrc + cid * 16, L + 8192 + cid * 16);
        }
        __syncthreads();   // drain staging; tile visible

        // ---- A fragments (zero-conflict slice reads)
        bf16x8 a0[4], a1[4];
        #pragma unroll
        for (int mt = 0; mt < 4; ++mt) {
            a0[mt] = *(const bf16x8*)(L + mt * 2048 + arow + p0);
            a1[mt] = *(const bf16x8*)(L + mt * 2048 + arow + p1);
        }
        // ---- MFMA: 2 kk x 5 j x 4 mt
        #pragma unroll
        for (int j = 0; j < 5; ++j) {
            const char* bs = L + 8192 + (ntb + j) * 2048 + arow;
            bf16x8 b0 = *(const bf16x8*)(bs + p0);
            #pragma unroll
            for (int mt = 0; mt < 4; ++mt)
                acc[mt][j] = __builtin_amdgcn_mfma_f32_16x16x32_bf16(a0[mt], b0, acc[mt][j], 0, 0, 0);
            bf16x8 b1 = *(const bf16x8*)(bs + p1);
            #pragma unroll
            for (int mt = 0; mt < 4; ++mt)
                acc[mt][j] = __builtin_amdgcn_mfma_f32_16x16x32_bf16(a1[mt], b1, acc[mt][j], 0, 0, 0);
        }
        __syncthreads();   // reads done before next stage overwrites
    }

    // ---- epilogue: features (cols < 256)
    #pragma unroll
    for (int j = 0; j < 5; ++j) {
        int col = (ntb + j) * 16 + ic;
        if (col < H_DIM) {
            float bias = bfv[col];
            #pragma unroll
            for (int mt = 0; mt < 4; ++mt) {
                #pragma unroll
                for (int i = 0; i < 4; ++i) {
                    int row = bm0 + mt * 16 + q * 4 + i;
                    float v = acc[mt][j][i] + bias;
                    v = v > 0.f ? v : 0.f;
                    feat[(size_t)row * H_DIM + col] = f2bf(v);
                }
            }
        }
    }
    // ---- router: wave 3 holds cols 256..319 in j=1..4
    if (w == 3) {
        #pragma unroll
        for (int mt = 0; mt < 4; ++mt) {
            #pragma unroll
            for (int i = 0; i < 4; ++i) {
                float m1 = -1e30f, m2 = -1e30f;
                int a1 = 0;
                #pragma unroll
                for (int j = 1; j < 5; ++j) {
                    int leaf = (j - 1) * 16 + ic;
                    float v = acc[mt][j][i] + brv[leaf];
                    if (v > m1) { m2 = m1; m1 = v; a1 = leaf; }
                    else if (v > m2) { m2 = v; }
                }
                #pragma unroll
                for (int s = 1; s < 16; s <<= 1) {
                    float om1 = __shfl_xor(m1, s, 64);
                    float om2 = __shfl_xor(m2, s, 64);
                    int   oa1 = __shfl_xor(a1, s, 64);
                    bool take = (om1 > m1) || (om1 == m1 && oa1 < a1);
                    float nm2 = take ? fmaxf(om2, m1) : fmaxf(m2, om1);
                    m1 = take ? om1 : m1;
                    a1 = take ? oa1 : a1;
                    m2 = nm2;
                }
                if (ic == 0) {
                    int row = bm0 + mt * 16 + q * 4 + i;
                    choices[row] = a1;
                    if (m1 - m2 < GAP_THRESH) {
                        unsigned int idx = atomicAdd(flagcnt, 1u);
                        flagrows[idx] = row;
                    }
                }
            }
        }
    }
}

// =================== FALLBACK PATH (r6, proven) ===================

__global__ void k0_prep32(const float* __restrict__ Wf, const float* __restrict__ Wr,
                          unsigned short* __restrict__ Wt, unsigned int* __restrict__ flagcnt) {
    if (blockIdx.x == 0 && threadIdx.x == 0) *flagcnt = 0u;
    int id = blockIdx.x * 256 + threadIdx.x;
    int ts = id / 1280;
    int r  = id % 1280;
    int n  = r % 320;
    int c  = r / 320;
    int dst = ts * BTILE2 + ((n * 64 + c * 16) ^ ((n & 7) << 4));
    int ks  = ts * 32 + c * 8;
    unsigned short v[8];
    #pragma unroll
    for (int j = 0; j < 8; ++j) {
        int k = ks + j;
        float f = 0.f;
        if (k < D_IN)
            f = (n < H_DIM) ? Wf[(size_t)k * H_DIM + n]
                            : Wr[(size_t)k * L_LEAF + (n - H_DIM)];
        v[j] = f2bf(f);
    }
    *(ushort8v*)((char*)Wt + dst) = *(ushort8v*)v;
}

__global__ __launch_bounds__(256, 4) void k1_direct(
    const float* __restrict__ x, const unsigned short* __restrict__ Wt,
    const float* __restrict__ bfv, const float* __restrict__ brv,
    unsigned short* __restrict__ feat, int* __restrict__ choices,
    unsigned int* __restrict__ flagcnt, int* __restrict__ flagrows)
{
    __shared__ __align__(16) unsigned short Bl[2][320 * 32];
    const int t = threadIdx.x, w = t >> 6, l = t & 63, q = l >> 4, ic = l & 15;
    const int bm0 = blockIdx.x * 64;
    const float* xbase = x + (size_t)(bm0 + ic) * D_IN;
    f32x4 acc[4][5];
    #pragma unroll
    for (int a = 0; a < 4; ++a)
        #pragma unroll
        for (int b = 0; b < 5; ++b)
            acc[a][b] = (f32x4){0.f, 0.f, 0.f, 0.f};
    const int rbB = (ic * 64 + (q << 4)) ^ ((ic & 7) << 4);
    const int ntb = w * 5;
    #pragma unroll
    for (int i = 0; i < 5; ++i) {
        int cid = i * 256 + t;
        gload_lds16((const char*)Wt + cid * 16, (char*)&Bl[0][0] + cid * 16);
    }
    __syncthreads();
    int cur = 0;
    for (int ts = 0; ts < NSTEP2; ++ts) {
        if (ts + 1 < NSTEP2) {
            const char* src = (const char*)Wt + (size_t)(ts + 1) * BTILE2;
            char* dst = (char*)&Bl[cur ^ 1][0];
            #pragma unroll
            for (int i = 0; i < 5; ++i) {
                int cid = i * 256 + t;
                gload_lds16(src + cid * 16, dst + cid * 16);
            }
        }
        const int kg = ts * 32 + q * 8;
        const bool ok = (kg + 8 <= D_IN);
        const int kgs = ok ? kg : 0;
        f32x4 an[4][2];
        #pragma unroll
        for (int mt = 0; mt < 4; ++mt) {
            const float* xr = xbase + (size_t)(mt * 16) * D_IN + kgs;
            an[mt][0] = *(const f32x4*)(xr);
            an[mt][1] = *(const f32x4*)(xr + 4);
        }
        bf16x8 af[4];
        #pragma unroll
        for (int mt = 0; mt < 4; ++mt) {
            union { unsigned int u[4]; bf16x8 v; } pk;
            f32x4 lo = an[mt][0], hi = an[mt][1];
            pk.u[0] = ok ? cvtpk(lo.x, lo.y) : 0u;
            pk.u[1] = ok ? cvtpk(lo.z, lo.w) : 0u;
            pk.u[2] = ok ? cvtpk(hi.x, hi.y) : 0u;
            pk.u[3] = ok ? cvtpk(hi.z, hi.w) : 0u;
            af[mt] = pk.v;
        }
        const char* Bc = (const char*)&Bl[cur][0];
        #pragma unroll
        for (int j = 0; j < 5; ++j) {
            bf16x8 b = *(const bf16x8*)(Bc + (ntb + j) * 1024 + rbB);
            #pragma unroll
            for (int mt = 0; mt < 4; ++mt)
                acc[mt][j] = __builtin_amdgcn_mfma_f32_16x16x32_bf16(af[mt], b, acc[mt][j], 0, 0, 0);
        }
        __syncthreads();
        cur ^= 1;
    }
    #pragma unroll
    for (int j = 0; j < 5; ++j) {
        int col = (ntb + j) * 16 + ic;
        if (col < H_DIM) {
            float bias = bfv[col];
            #pragma unroll
            for (int mt = 0; mt < 4; ++mt) {
                #pragma unroll
                for (int i = 0; i < 4; ++i) {
                    int row = bm0 + mt * 16 + q * 4 + i;
                    float v = acc[mt][j][i] + bias;
                    v = v > 0.f ? v : 0.f;
                    feat[(size_t)row * H_DIM + col] = f2bf(v);
                }
            }
        }
    }
    if (w == 3) {
        #pragma unroll
        for (int mt = 0; mt < 4; ++mt) {
            #pragma unroll
            for (int i = 0; i < 4; ++i) {
                float m1 = -1e30f, m2 = -1e30f;
                int a1 = 0;
                #pragma unroll
                for (int j = 1; j < 5; ++j) {
                    int leaf = (j - 1) * 16 + ic;
                    float v = acc[mt][j][i] + brv[leaf];
                    if (v > m1) { m2 = m1; m1 = v; a1 = leaf; }
                    else if (v > m2) { m2 = v; }
                }
                #pragma unroll
                for (int s = 1; s < 16; s <<= 1) {
                    float om1 = __shfl_xor(m1, s, 64);
                    float om2 = __shfl_xor(m2, s, 64);
                    int   oa1 = __shfl_xor(a1, s, 64);
                    bool take = (om1 > m1) || (om1 == m1 && oa1 < a1);
                    float nm2 = take ? fmaxf(om2, m1) : fmaxf(m2, om1);
                    m1 = take ? om1 : m1;
                    a1 = take ? oa1 : a1;
                    m2 = nm2;
                }
                if (ic == 0) {
                    int row = bm0 + mt * 16 + q * 4 + i;
                    choices[row] = a1;
                    if (m1 - m2 < GAP_THRESH) {
                        unsigned int idx = atomicAdd(flagcnt, 1u);
                        flagrows[idx] = row;
                    }
                }
            }
        }
    }
}

// =================== shared K2 / K3 ===================

__global__ __launch_bounds__(256) void k2_exact(
    const float* __restrict__ x, const float* __restrict__ Wr,
    const float* __restrict__ brv, const unsigned int* __restrict__ flagcnt,
    const int* __restrict__ flagrows, int* __restrict__ choices)
{
    __shared__ float wl[64 * 64];
    __shared__ float xl[4][64];
    const unsigned int cnt = *flagcnt;
    const int t = threadIdx.x, w = t >> 6, l = t & 63;
    for (unsigned int base = blockIdx.x * 4u; base < cnt; base += gridDim.x * 4u) {
        unsigned int ri = base + w;
        int row = (ri < cnt) ? flagrows[ri] : 0;
        const float* xr = x + (size_t)row * D_IN;
        float s0 = 0.f, s1 = 0.f, s2 = 0.f, s3 = 0.f;
        for (int kt = 0; kt < 13; ++kt) {
            int k0 = kt * 64;
            #pragma unroll
            for (int i = 0; i < 4; ++i) {
                int flat = i * 256 + t;
                int kk = flat >> 4, lq = (flat & 15) * 4;
                int kgk = k0 + kk;
                f32x4 v = (f32x4){0.f, 0.f, 0.f, 0.f};
                if (kgk < D_IN) v = *(const f32x4*)(Wr + (size_t)kgk * L_LEAF + lq);
                *(f32x4*)&wl[kk * 64 + lq] = v;
            }
            xl[w][l] = (k0 + l < D_IN) ? xr[k0 + l] : 0.f;
            __syncthreads();
            #pragma unroll
            for (int kk = 0; kk < 64; kk += 4) {
                s0 = fmaf(xl[w][kk    ], wl[(kk    ) * 64 + l], s0);
                s1 = fmaf(xl[w][kk + 1], wl[(kk + 1) * 64 + l], s1);
                s2 = fmaf(xl[w][kk + 2], wl[(kk + 2) * 64 + l], s2);
                s3 = fmaf(xl[w][kk + 3], wl[(kk + 3) * 64 + l], s3);
            }
            __syncthreads();
        }
        float v = (s0 + s1) + (s2 + s3) + brv[l];
        int a = l;
        #pragma unroll
        for (int st = 1; st < 64; st <<= 1) {
            float ov = __shfl_xor(v, st, 64);
            int   oa = __shfl_xor(a, st, 64);
            if (ov > v || (ov == v && oa < a)) { v = ov; a = oa; }
        }
        if (l == 0 && ri < cnt) choices[row] = a;
    }
}

__global__ __launch_bounds__(256) void k3_leaf(
    const unsigned short* __restrict__ feat, const int* __restrict__ choices,
    const float* __restrict__ Wl, const unsigned short* __restrict__ Wlb,
    const float* __restrict__ blv, float* __restrict__ out)
{
    const int t = threadIdx.x, wv = t >> 6, l = t & 63, g = l >> 4, i = l & 15;
    const int row = blockIdx.x * 16 + wv * 4 + g;
    const int leaf = choices[row];

    ushort8v f0 = *(const ushort8v*)(feat + (size_t)row * H_DIM + i * 16);
    ushort8v f1 = *(const ushort8v*)(feat + (size_t)row * H_DIM + i * 16 + 8);
    float fv[16];
    #pragma unroll
    for (int j = 0; j < 8; ++j) { fv[j] = bf2f(f0[j]); fv[8 + j] = bf2f(f1[j]); }

    float acc[C_CLS];
    #pragma unroll
    for (int c = 0; c < C_CLS; ++c) acc[c] = 0.f;

    if (Wlb) {
        const unsigned short* wp = Wlb + ((size_t)leaf * H_DIM + i * 16) * C_CLS;
        ushort8v wreg[20];
        #pragma unroll
        for (int j = 0; j < 20; ++j) wreg[j] = *(const ushort8v*)(wp + j * 8);
        #pragma unroll
        for (int h = 0; h < 16; ++h) {
            #pragma unroll
            for (int c = 0; c < C_CLS; ++c) {
                int e = h * C_CLS + c;
                acc[c] = fmaf(fv[h], bf2f(wreg[e >> 3][e & 7]), acc[c]);
            }
        }
    } else {
        const float* wp = Wl + ((size_t)leaf * H_DIM + i * 16) * C_CLS;
        #pragma unroll
        for (int h = 0; h < 16; ++h) {
            #pragma unroll
            for (int c = 0; c < C_CLS; ++c)
                acc[c] = fmaf(fv[h], wp[h * C_CLS + c], acc[c]);
        }
    }
    #pragma unroll
    for (int st = 1; st < 16; st <<= 1) {
        #pragma unroll
        for (int c = 0; c < C_CLS; ++c) acc[c] += __shfl_xor(acc[c], st, 64);
    }
    if (i == 0) {
        #pragma unroll
        for (int c = 0; c < C_CLS; ++c)
            out[(size_t)row * C_CLS + c] = acc[c] + blv[leaf * C_CLS + c];
    }
}

// ---------------- launcher ----------------
extern "C" void kernel_launch(void* const* d_in, const int* in_sizes, int n_in,
                              void* d_out, int out_size, void* d_ws, size_t ws_size,
                              hipStream_t stream) {
    if (ws_size < WS_BASE) return;   // loud fail
    const bool use_bf = ws_size >= WS_WLB;
    const bool use_xt = ws_size >= WS_XT;

    const float* x   = (const float*)d_in[0];
    const float* Wf  = (const float*)d_in[1];
    const float* bfv = (const float*)d_in[2];
    const float* Wr  = (const float*)d_in[3];
    const float* brv = (const float*)d_in[4];
    const float* Wl  = (const float*)d_in[5];
    const float* blv = (const float*)d_in[6];
    float* out = (float*)d_out;

    char* ws = (char*)d_ws;
    unsigned int*   flagcnt  = (unsigned int*)(ws + O_FLAGCNT);
    int*            choices  = (int*)(ws + O_CHOICES);
    int*            flagrows = (int*)(ws + O_FLAGROWS);
    unsigned short* Wt       = (unsigned short*)(ws + O_WT);
    unsigned short* feat     = (unsigned short*)(ws + O_FEAT);
    unsigned short* Wlb      = use_bf ? (unsigned short*)(ws + O_WLB) : (unsigned short*)0;
    unsigned short* Xt       = (unsigned short*)(ws + O_XT);

    if (use_bf)
        hipLaunchKernelGGL(k0b_wl, dim3(160), dim3(256), 0, stream, Wl, Wlb);

    if (use_xt) {
        hipLaunchKernelGGL(k0_prep64, dim3(130), dim3(256), 0, stream, Wf, Wr, Wt, flagcnt);
        hipLaunchKernelGGL(k0x, dim3(26624), dim3(256), 0, stream, x, Xt);
        hipLaunchKernelGGL(k1_xt, dim3(B_ROWS / 64), dim3(256), 0, stream,
                           Xt, Wt, bfv, brv, feat, choices, flagcnt, flagrows);
    } else {
        hipLaunchKernelGGL(k0_prep32, dim3(125), dim3(256), 0, stream, Wf, Wr, Wt, flagcnt);
        hipLaunchKernelGGL(k1_direct, dim3(B_ROWS / 64), dim3(256), 0, stream,
                           x, Wt, bfv, brv, feat, choices, flagcnt, flagrows);
    }
    hipLaunchKernelGGL(k2_exact, dim3(1024), dim3(256), 0, stream,
                       x, Wr, brv, flagcnt, flagrows, choices);
    hipLaunchKernelGGL(k3_leaf, dim3(B_ROWS / 16), dim3(256), 0, stream,
                       feat, choices, Wl, Wlb, blv, out);
}

// Round 9
// 198.871 us; speedup vs baseline: 1.2274x; 1.2274x over previous
//
#include <hip/hip_runtime.h>
#include <stdint.h>

// ---------------- problem constants ----------------
#define B_ROWS 65536
#define D_IN   784
#define H_DIM  256
#define L_LEAF 64
#define C_CLS  10
#define NSTEP2 25            // ceil(784/32) K-steps of 32
#define BTILE2 20480         // 320 n * 32 k * 2B per K-step tile
#define GAP_THRESH 0.03f

using f32x4    = __attribute__((ext_vector_type(4))) float;
using bf16x8   = __attribute__((ext_vector_type(8))) short;
using ushort8v = __attribute__((ext_vector_type(8))) unsigned short;
using ushort4v = __attribute__((ext_vector_type(4))) unsigned short;

// ---------------- ws layout (bytes) ----------------
#define O_FLAGCNT  0
#define O_CHOICES  4096
#define O_FLAGROWS (O_CHOICES + B_ROWS * 4)
#define O_WT       (O_FLAGROWS + B_ROWS * 4)
#define O_FEAT     (O_WT + NSTEP2 * BTILE2)
#define O_WLB      (O_FEAT + (size_t)B_ROWS * H_DIM * 2)
#define WLB_BYTES  ((size_t)L_LEAF * H_DIM * C_CLS * 2)
#define WS_BASE    O_WLB
#define WS_WLB     (O_WLB + WLB_BYTES)

__device__ __forceinline__ unsigned short f2bf(float f) {
    union { float f; unsigned int u; } c; c.f = f;
    unsigned int u = c.u;
    return (unsigned short)((u + 0x7fffu + ((u >> 16) & 1u)) >> 16);   // RNE
}
__device__ __forceinline__ float bf2f(unsigned short u) {
    union { unsigned int u; float f; } c; c.u = ((unsigned int)u) << 16;
    return c.f;
}
__device__ __forceinline__ unsigned int cvtpk(float a, float b) {
    unsigned int r;
    asm("v_cvt_pk_bf16_f32 %0, %1, %2" : "=v"(r) : "v"(a), "v"(b));
    return r;
}
__device__ __forceinline__ void gload_lds16(const void* g, void* l) {
    __builtin_amdgcn_global_load_lds(
        (const __attribute__((address_space(1))) unsigned int*)g,
        (__attribute__((address_space(3))) unsigned int*)l, 16, 0, 0);
}

// ---------------- K0: swizzled B image (BK=32), r6-proven ----------------
// chunk (n, c in 0..3) at byte ts*20480 + ((n*64 + c*16) ^ ((n&7)<<4)),
// content k = ts*32 + c*8 (bf16; zero-padded past 784).
__global__ void k0_prep32(const float* __restrict__ Wf, const float* __restrict__ Wr,
                          unsigned short* __restrict__ Wt, unsigned int* __restrict__ flagcnt) {
    if (blockIdx.x == 0 && threadIdx.x == 0) *flagcnt = 0u;
    int id = blockIdx.x * 256 + threadIdx.x;
    int ts = id / 1280;
    int r  = id % 1280;
    int n  = r % 320;
    int c  = r / 320;
    int dst = ts * BTILE2 + ((n * 64 + c * 16) ^ ((n & 7) << 4));
    int ks  = ts * 32 + c * 8;
    unsigned short v[8];
    #pragma unroll
    for (int j = 0; j < 8; ++j) {
        int k = ks + j;
        float f = 0.f;
        if (k < D_IN)
            f = (n < H_DIM) ? Wf[(size_t)k * H_DIM + n]
                            : Wr[(size_t)k * L_LEAF + (n - H_DIM)];
        v[j] = f2bf(f);
    }
    *(ushort8v*)((char*)Wt + dst) = *(ushort8v*)v;
}

// ---------------- K0b: Wl -> bf16 ----------------
__global__ void k0b_wl(const float* __restrict__ Wl, unsigned short* __restrict__ Wlb) {
    int i = (blockIdx.x * 256 + threadIdx.x) * 4;
    f32x4 v = *(const f32x4*)(Wl + i);
    ushort4v h; h.x = f2bf(v.x); h.y = f2bf(v.y); h.z = f2bf(v.z); h.w = f2bf(v.w);
    *(ushort4v*)(Wlb + i) = h;
}

// ---------------- K1: counted-vmcnt 3-deep pipelined dual GEMM ----------------
// grid = 512 x 512 thr (8 waves = 2M x 4N). BM=128, BK=32.
// LDS buf = A(fp32,16KB) + B(bf16,20KB) = 36KB; 3-deep = 108KB -> 1 block/CU.
// Per step: vmcnt(4); s_barrier; stage(t+2); compute(t). Loads span 2 steps.
// BUGFIX r9: A chunks are fp32 (16B = 4 floats): content k = ts*32 + c8*4
// (r8 used c8*8 — bf16 convention — staging wrong k-ranges; absmax 5.4).
#define BUFB 36864
__global__ __launch_bounds__(512, 1) void k1_pipe(
    const float* __restrict__ x, const unsigned short* __restrict__ Wt,
    const float* __restrict__ bfv, const float* __restrict__ brv,
    unsigned short* __restrict__ feat, int* __restrict__ choices,
    unsigned int* __restrict__ flagcnt, int* __restrict__ flagrows)
{
    __shared__ __align__(16) char L[3 * BUFB];

    const int t  = threadIdx.x;
    const int w  = t >> 6, l = t & 63, q = l >> 4, ic = l & 15;
    const int wm = w >> 2, wn = w & 3;          // 2 M-groups x 4 N-groups
    const int bm0 = blockIdx.x * 128;
    const int ntb = wn * 5;                     // wave's first N-tile

    f32x4 acc[4][5];
    #pragma unroll
    for (int a = 0; a < 4; ++a)
        #pragma unroll
        for (int b = 0; b < 5; ++b)
            acc[a][b] = (f32x4){0.f, 0.f, 0.f, 0.f};

    const int e7  = ic & 7;
    const int pA0 = ((2 * q)     ^ e7) << 4;    // content fp32-chunk 2q   (k = 8q..8q+3)
    const int pA1 = ((2 * q + 1) ^ e7) << 4;    // content fp32-chunk 2q+1 (k = 8q+4..8q+7)
    const int rbB = (ic * 64 + (q << 4)) ^ (e7 << 4);   // B swizzled offset (r6)

    // A: 1024 chunks (thread t: t, t+512): chunk i=(r,p): r=i>>3, p=i&7,
    //    content c8 = p ^ (r&7), k = ts*32 + c8*4 fp32 (addr-clamped; B zero-pads).
    // B: 1280 chunks (t, t+512, and t+1024 for t<256), linear from Wt image.
#define STAGE(TS, LB)                                                          \
    {                                                                          \
        const int ts_ = (TS);                                                  \
        char* Lb_ = (LB);                                                      \
        _Pragma("unroll")                                                      \
        for (int h = 0; h < 2; ++h) {                                          \
            int i_ = h * 512 + t;                                              \
            int r_ = i_ >> 3, p_ = i_ & 7;                                     \
            int c8_ = p_ ^ (r_ & 7);                                           \
            int k_ = ts_ * 32 + c8_ * 4;                                       \
            int ko_ = (k_ + 4 <= D_IN) ? k_ : 0;                               \
            gload_lds16(x + (size_t)(bm0 + r_) * D_IN + ko_, Lb_ + i_ * 16);   \
        }                                                                      \
        const char* bs_ = (const char*)Wt + (size_t)ts_ * BTILE2;              \
        char* bd_ = Lb_ + 16384;                                               \
        gload_lds16(bs_ + t * 16,          bd_ + t * 16);                      \
        gload_lds16(bs_ + (512 + t) * 16,  bd_ + (512 + t) * 16);              \
        if (t < 256)                                                           \
            gload_lds16(bs_ + (1024 + t) * 16, bd_ + (1024 + t) * 16);         \
    }

    // ---- prologue: two tiles in flight
    STAGE(0, L);
    STAGE(1, L + BUFB);

    for (int ts = 0; ts < NSTEP2; ++ts) {
        // own stage(ts) complete; stage(ts+1) may remain in flight (counted!)
        if (ts < NSTEP2 - 1)
            asm volatile("s_waitcnt vmcnt(4)\ns_barrier" ::: "memory");
        else
            asm volatile("s_waitcnt vmcnt(0)\ns_barrier" ::: "memory");

        if (ts + 2 < NSTEP2) {
            char* nb = L + ((ts + 2) % 3) * BUFB;
            STAGE(ts + 2, nb);
        }

        const char* Lc = L + (ts % 3) * BUFB;
        // ---- A fragments: fp32 from LDS, cvt_pk to bf16
        bf16x8 af[4];
        #pragma unroll
        for (int mt = 0; mt < 4; ++mt) {
            const char* rowp = Lc + (wm * 64 + mt * 16 + ic) * 128;
            f32x4 lo = *(const f32x4*)(rowp + pA0);
            f32x4 hi = *(const f32x4*)(rowp + pA1);
            union { unsigned int u[4]; bf16x8 v; } pk;
            pk.u[0] = cvtpk(lo.x, lo.y);
            pk.u[1] = cvtpk(lo.z, lo.w);
            pk.u[2] = cvtpk(hi.x, hi.y);
            pk.u[3] = cvtpk(hi.z, hi.w);
            af[mt] = pk.v;
        }
        // ---- MFMA cluster
        const char* Bb = Lc + 16384;
        __builtin_amdgcn_s_setprio(1);
        #pragma unroll
        for (int j = 0; j < 5; ++j) {
            bf16x8 b = *(const bf16x8*)(Bb + (ntb + j) * 1024 + rbB);
            #pragma unroll
            for (int mt = 0; mt < 4; ++mt)
                acc[mt][j] = __builtin_amdgcn_mfma_f32_16x16x32_bf16(af[mt], b, acc[mt][j], 0, 0, 0);
        }
        __builtin_amdgcn_s_setprio(0);
    }
#undef STAGE

    // ---- epilogue: features (cols < 256)
    #pragma unroll
    for (int j = 0; j < 5; ++j) {
        int col = (ntb + j) * 16 + ic;
        if (col < H_DIM) {
            float bias = bfv[col];
            #pragma unroll
            for (int mt = 0; mt < 4; ++mt) {
                #pragma unroll
                for (int i = 0; i < 4; ++i) {
                    int row = bm0 + wm * 64 + mt * 16 + q * 4 + i;
                    float v = acc[mt][j][i] + bias;
                    v = v > 0.f ? v : 0.f;
                    feat[(size_t)row * H_DIM + col] = f2bf(v);
                }
            }
        }
    }
    // ---- router: wn==3 waves hold cols 256..319 in j=1..4
    if (wn == 3) {
        #pragma unroll
        for (int mt = 0; mt < 4; ++mt) {
            #pragma unroll
            for (int i = 0; i < 4; ++i) {
                float m1 = -1e30f, m2 = -1e30f;
                int a1 = 0;
                #pragma unroll
                for (int j = 1; j < 5; ++j) {
                    int leaf = (j - 1) * 16 + ic;
                    float v = acc[mt][j][i] + brv[leaf];
                    if (v > m1) { m2 = m1; m1 = v; a1 = leaf; }
                    else if (v > m2) { m2 = v; }
                }
                #pragma unroll
                for (int s = 1; s < 16; s <<= 1) {
                    float om1 = __shfl_xor(m1, s, 64);
                    float om2 = __shfl_xor(m2, s, 64);
                    int   oa1 = __shfl_xor(a1, s, 64);
                    bool take = (om1 > m1) || (om1 == m1 && oa1 < a1);
                    float nm2 = take ? fmaxf(om2, m1) : fmaxf(m2, om1);
                    m1 = take ? om1 : m1;
                    a1 = take ? oa1 : a1;
                    m2 = nm2;
                }
                if (ic == 0) {
                    int row = bm0 + wm * 64 + mt * 16 + q * 4 + i;
                    choices[row] = a1;
                    if (m1 - m2 < GAP_THRESH) {
                        unsigned int idx = atomicAdd(flagcnt, 1u);
                        flagrows[idx] = row;
                    }
                }
            }
        }
    }
}

// ---------------- K2: exact fp32 router for flagged rows ----------------
__global__ __launch_bounds__(256) void k2_exact(
    const float* __restrict__ x, const float* __restrict__ Wr,
    const float* __restrict__ brv, const unsigned int* __restrict__ flagcnt,
    const int* __restrict__ flagrows, int* __restrict__ choices)
{
    __shared__ float wl[64 * 64];
    __shared__ float xl[4][64];
    const unsigned int cnt = *flagcnt;
    const int t = threadIdx.x, w = t >> 6, l = t & 63;
    for (unsigned int base = blockIdx.x * 4u; base < cnt; base += gridDim.x * 4u) {
        unsigned int ri = base + w;
        int row = (ri < cnt) ? flagrows[ri] : 0;
        const float* xr = x + (size_t)row * D_IN;
        float s0 = 0.f, s1 = 0.f, s2 = 0.f, s3 = 0.f;
        for (int kt = 0; kt < 13; ++kt) {
            int k0 = kt * 64;
            #pragma unroll
            for (int i = 0; i < 4; ++i) {
                int flat = i * 256 + t;
                int kk = flat >> 4, lq = (flat & 15) * 4;
                int kgk = k0 + kk;
                f32x4 v = (f32x4){0.f, 0.f, 0.f, 0.f};
                if (kgk < D_IN) v = *(const f32x4*)(Wr + (size_t)kgk * L_LEAF + lq);
                *(f32x4*)&wl[kk * 64 + lq] = v;
            }
            xl[w][l] = (k0 + l < D_IN) ? xr[k0 + l] : 0.f;
            __syncthreads();
            #pragma unroll
            for (int kk = 0; kk < 64; kk += 4) {
                s0 = fmaf(xl[w][kk    ], wl[(kk    ) * 64 + l], s0);
                s1 = fmaf(xl[w][kk + 1], wl[(kk + 1) * 64 + l], s1);
                s2 = fmaf(xl[w][kk + 2], wl[(kk + 2) * 64 + l], s2);
                s3 = fmaf(xl[w][kk + 3], wl[(kk + 3) * 64 + l], s3);
            }
            __syncthreads();
        }
        float v = (s0 + s1) + (s2 + s3) + brv[l];
        int a = l;
        #pragma unroll
        for (int st = 1; st < 64; st <<= 1) {
            float ov = __shfl_xor(v, st, 64);
            int   oa = __shfl_xor(a, st, 64);
            if (ov > v || (ov == v && oa < a)) { v = ov; a = oa; }
        }
        if (l == 0 && ri < cnt) choices[row] = a;
    }
}

// ---------------- K3: per-row leaf matvec ----------------
__global__ __launch_bounds__(256) void k3_leaf(
    const unsigned short* __restrict__ feat, const int* __restrict__ choices,
    const float* __restrict__ Wl, const unsigned short* __restrict__ Wlb,
    const float* __restrict__ blv, float* __restrict__ out)
{
    const int t = threadIdx.x, wv = t >> 6, l = t & 63, g = l >> 4, i = l & 15;
    const int row = blockIdx.x * 16 + wv * 4 + g;
    const int leaf = choices[row];

    ushort8v f0 = *(const ushort8v*)(feat + (size_t)row * H_DIM + i * 16);
    ushort8v f1 = *(const ushort8v*)(feat + (size_t)row * H_DIM + i * 16 + 8);
    float fv[16];
    #pragma unroll
    for (int j = 0; j < 8; ++j) { fv[j] = bf2f(f0[j]); fv[8 + j] = bf2f(f1[j]); }

    float acc[C_CLS];
    #pragma unroll
    for (int c = 0; c < C_CLS; ++c) acc[c] = 0.f;

    if (Wlb) {
        const unsigned short* wp = Wlb + ((size_t)leaf * H_DIM + i * 16) * C_CLS;
        ushort8v wreg[20];
        #pragma unroll
        for (int j = 0; j < 20; ++j) wreg[j] = *(const ushort8v*)(wp + j * 8);
        #pragma unroll
        for (int h = 0; h < 16; ++h) {
            #pragma unroll
            for (int c = 0; c < C_CLS; ++c) {
                int e = h * C_CLS + c;
                acc[c] = fmaf(fv[h], bf2f(wreg[e >> 3][e & 7]), acc[c]);
            }
        }
    } else {
        const float* wp = Wl + ((size_t)leaf * H_DIM + i * 16) * C_CLS;
        #pragma unroll
        for (int h = 0; h < 16; ++h) {
            #pragma unroll
            for (int c = 0; c < C_CLS; ++c)
                acc[c] = fmaf(fv[h], wp[h * C_CLS + c], acc[c]);
        }
    }
    #pragma unroll
    for (int st = 1; st < 16; st <<= 1) {
        #pragma unroll
        for (int c = 0; c < C_CLS; ++c) acc[c] += __shfl_xor(acc[c], st, 64);
    }
    if (i == 0) {
        #pragma unroll
        for (int c = 0; c < C_CLS; ++c)
            out[(size_t)row * C_CLS + c] = acc[c] + blv[leaf * C_CLS + c];
    }
}

// ---------------- launcher ----------------
extern "C" void kernel_launch(void* const* d_in, const int* in_sizes, int n_in,
                              void* d_out, int out_size, void* d_ws, size_t ws_size,
                              hipStream_t stream) {
    if (ws_size < WS_BASE) return;   // loud fail
    const bool use_bf = ws_size >= WS_WLB;

    const float* x   = (const float*)d_in[0];
    const float* Wf  = (const float*)d_in[1];
    const float* bfv = (const float*)d_in[2];
    const float* Wr  = (const float*)d_in[3];
    const float* brv = (const float*)d_in[4];
    const float* Wl  = (const float*)d_in[5];
    const float* blv = (const float*)d_in[6];
    float* out = (float*)d_out;

    char* ws = (char*)d_ws;
    unsigned int*   flagcnt  = (unsigned int*)(ws + O_FLAGCNT);
    int*            choices  = (int*)(ws + O_CHOICES);
    int*            flagrows = (int*)(ws + O_FLAGROWS);
    unsigned short* Wt       = (unsigned short*)(ws + O_WT);
    unsigned short* feat     = (unsigned short*)(ws + O_FEAT);
    unsigned short* Wlb      = use_bf ? (unsigned short*)(ws + O_WLB) : (unsigned short*)0;

    hipLaunchKernelGGL(k0_prep32, dim3(125), dim3(256), 0, stream, Wf, Wr, Wt, flagcnt);
    if (use_bf)
        hipLaunchKernelGGL(k0b_wl, dim3(160), dim3(256), 0, stream, Wl, Wlb);
    hipLaunchKernelGGL(k1_pipe, dim3(B_ROWS / 128), dim3(512), 0, stream,
                       x, Wt, bfv, brv, feat, choices, flagcnt, flagrows);
    hipLaunchKernelGGL(k2_exact, dim3(1024), dim3(256), 0, stream,
                       x, Wr, brv, flagcnt, flagrows, choices);
    hipLaunchKernelGGL(k3_leaf, dim3(B_ROWS / 16), dim3(256), 0, stream,
                       feat, choices, Wl, Wlb, blv, out);
}